// Round 2
// baseline (436.252 us; speedup 1.0000x reference)
//
#include <hip/hip_runtime.h>
#include <cstdint>
#include <cstddef>

// ---------------------------------------------------------------------------
// out = cos(x @ Wp^T + phi) @ Wc^T
//   x: [32768,1024] fp32, Wp/Wc: [1024,1024] fp32, phi flat [1024] fp32.
// R2: x-cast fused into GEMM1 (fp32 global -> reg -> bf16 ds_write, prefetch
// double-buffered in registers); W casts merged into one launch.
// GEMM core: m97 structure, 128x128 tile, BK=32, 16x16x32 bf16 MFMA.
// ---------------------------------------------------------------------------

typedef __attribute__((ext_vector_type(8))) short short8;
typedef __attribute__((ext_vector_type(4))) float f32x4;

__device__ __forceinline__ unsigned short f2bf(float f) {
  unsigned u = __float_as_uint(f);
  u += 0x7FFFu + ((u >> 16) & 1u);   // RNE
  return (unsigned short)(u >> 16);
}

// pack two fp32 -> bf16x2 (round-half-up; tie bias negligible vs 4.8x margin)
__device__ __forceinline__ unsigned pack2bf(float lo, float hi) {
  return ((__float_as_uint(lo) + 0x8000u) >> 16) |
         ((__float_as_uint(hi) + 0x8000u) & 0xFFFF0000u);
}

__device__ __forceinline__ void async_load16(const void* g, const void* l) {
  __builtin_amdgcn_global_load_lds(
      (const __attribute__((address_space(1))) void*)g,
      (__attribute__((address_space(3))) void*)l,
      16, 0, 0);
}

// --------------------- Wp + Wc fp32 -> bf16 (one launch) --------------------
__global__ __launch_bounds__(256) void cast_w(
    const float* __restrict__ Wp, const float* __restrict__ Wc,
    unsigned short* __restrict__ dp, unsigned short* __restrict__ dc) {
  int i = (blockIdx.x * 256 + threadIdx.x) * 4;   // 0 .. 2097151
  const float* s;
  unsigned short* d;
  int j;
  if (i < 1048576) { s = Wp; d = dp; j = i; }
  else             { s = Wc; d = dc; j = i - 1048576; }
  const float4 v = *(const float4*)(s + j);
  ushort4 o;
  o.x = f2bf(v.x); o.y = f2bf(v.y); o.z = f2bf(v.z); o.w = f2bf(v.w);
  *(ushort4*)(d + j) = o;
}

constexpr int TM = 128, TN = 128, BK = 32;
constexpr int Kdim = 1024, Ndim = 1024;

// ------------------- GEMM1: Q = cos(x @ Wp^T + phi), bf16 out ---------------
// A (x) is fp32; staged via reg round-trip with one-iter register prefetch.
__global__ __launch_bounds__(256, 2) void gemm1_fused(
    const float* __restrict__ X,            // [32768,1024] fp32
    const unsigned short* __restrict__ B,   // Wp bf16 [1024,1024]
    const float* __restrict__ phi,          // [1024]
    unsigned short* __restrict__ Q) {       // [32768,1024] bf16
  __shared__ unsigned short As[TM * BK];    // 8 KB
  __shared__ unsigned short Bs[TN * BK];    // 8 KB

  const int tid  = threadIdx.x;
  const int lane = tid & 63;
  const int wv   = tid >> 6;
  const int m_blk = blockIdx.x >> 3;
  const int n_blk = blockIdx.x & 7;
  const long row0 = (long)m_blk * TM;
  const int  col0 = n_blk * TN;

  // A staging: thread t covers row rowA = t>>1, k-halftile halfA = t&1 (16 fp32)
  const int rowA  = tid >> 1;
  const int halfA = tid & 1;
  const float* gA = X + (row0 + rowA) * Kdim + halfA * 16;
  unsigned* wA = (unsigned*)(As + rowA * BK + halfA * 16);  // 32B-aligned

  // B staging (async DMA): wave-uniform base + lane*16
  const int s_row  = lane >> 2;
  const int s_colb = (lane & 3) * 16;

  const int lane15 = lane & 15;
  const int quad   = lane >> 4;
  const int wm = (wv >> 1) * 64;
  const int wn = (wv & 1) * 64;

  f32x4 acc[4][4];
#pragma unroll
  for (int mi = 0; mi < 4; ++mi)
#pragma unroll
    for (int ni = 0; ni < 4; ++ni) {
      f32x4 z = {0.f, 0.f, 0.f, 0.f};
      acc[mi][ni] = z;
    }

  // register prefetch of first A k-tile (16 fp32 per thread)
  float4 a0, a1, a2, a3;
  {
    const float4* p = (const float4*)(gA);
    a0 = p[0]; a1 = p[1]; a2 = p[2]; a3 = p[3];
  }

  for (int k0 = 0; k0 < Kdim; k0 += BK) {
    // cvt + LDS write of current A tile (regs loaded last iter)
    wA[0] = pack2bf(a0.x, a0.y); wA[1] = pack2bf(a0.z, a0.w);
    wA[2] = pack2bf(a1.x, a1.y); wA[3] = pack2bf(a1.z, a1.w);
    wA[4] = pack2bf(a2.x, a2.y); wA[5] = pack2bf(a2.z, a2.w);
    wA[6] = pack2bf(a3.x, a3.y); wA[7] = pack2bf(a3.z, a3.w);
    // B tile DMA
#pragma unroll
    for (int j = 0; j < 2; ++j) {
      const int chunk = wv * 2 + j;
      const int row = chunk * 16 + s_row;
      const char* gb = (const char*)(B + (long)(col0 + row) * Kdim + k0) + s_colb;
      async_load16(gb, (const char*)Bs + chunk * 1024);
    }
    __syncthreads();

    // prefetch next A k-tile during MFMA phase (wraps harmlessly on last iter)
    {
      const int kn = (k0 + BK) & (Kdim - 1);
      const float4* p = (const float4*)(gA + kn);
      a0 = p[0]; a1 = p[1]; a2 = p[2]; a3 = p[3];
    }

    short8 af[4], bfr[4];
#pragma unroll
    for (int mi = 0; mi < 4; ++mi)
      af[mi] = *(const short8*)(As + (wm + mi * 16 + lane15) * BK + quad * 8);
#pragma unroll
    for (int ni = 0; ni < 4; ++ni)
      bfr[ni] = *(const short8*)(Bs + (wn + ni * 16 + lane15) * BK + quad * 8);
#pragma unroll
    for (int mi = 0; mi < 4; ++mi)
#pragma unroll
      for (int ni = 0; ni < 4; ++ni)
        acc[mi][ni] = __builtin_amdgcn_mfma_f32_16x16x32_bf16(
            af[mi], bfr[ni], acc[mi][ni], 0, 0, 0);
    __syncthreads();
  }

  // epilogue: cos(acc + phi[col]) -> bf16.  C/D: col=lane&15, row=quad*4+reg
  float ph[4];
#pragma unroll
  for (int ni = 0; ni < 4; ++ni)
    ph[ni] = phi[col0 + wn + ni * 16 + lane15];
#pragma unroll
  for (int mi = 0; mi < 4; ++mi) {
    const long rbase = row0 + wm + mi * 16 + quad * 4;
#pragma unroll
    for (int ni = 0; ni < 4; ++ni) {
      const int c = col0 + wn + ni * 16 + lane15;
#pragma unroll
      for (int r = 0; r < 4; ++r) {
        float v = __cosf(acc[mi][ni][r] + ph[ni]);
        Q[(rbase + r) * Ndim + c] = f2bf(v);
      }
    }
  }
}

// ---------------- GEMM2: out = Q @ Wc^T, bf16 in, fp32 out ------------------
__global__ __launch_bounds__(256, 2) void gemm2_bt(
    const unsigned short* __restrict__ A,   // Q bf16 [32768,1024]
    const unsigned short* __restrict__ B,   // Wc bf16 [1024,1024]
    float* __restrict__ C) {                // [32768,1024] fp32
  __shared__ unsigned short As[TM * BK];
  __shared__ unsigned short Bs[TN * BK];

  const int tid  = threadIdx.x;
  const int lane = tid & 63;
  const int wv   = tid >> 6;
  const int m_blk = blockIdx.x >> 3;
  const int n_blk = blockIdx.x & 7;
  const long row0 = (long)m_blk * TM;
  const int  col0 = n_blk * TN;

  const int s_row  = lane >> 2;
  const int s_colb = (lane & 3) * 16;

  const int lane15 = lane & 15;
  const int quad   = lane >> 4;
  const int wm = (wv >> 1) * 64;
  const int wn = (wv & 1) * 64;

  f32x4 acc[4][4];
#pragma unroll
  for (int mi = 0; mi < 4; ++mi)
#pragma unroll
    for (int ni = 0; ni < 4; ++ni) {
      f32x4 z = {0.f, 0.f, 0.f, 0.f};
      acc[mi][ni] = z;
    }

  for (int k0 = 0; k0 < Kdim; k0 += BK) {
#pragma unroll
    for (int j = 0; j < 2; ++j) {
      const int chunk = wv * 2 + j;
      const int row = chunk * 16 + s_row;
      const char* ga = (const char*)(A + (row0 + row) * Kdim + k0) + s_colb;
      async_load16(ga, (const char*)As + chunk * 1024);
      const char* gb = (const char*)(B + (long)(col0 + row) * Kdim + k0) + s_colb;
      async_load16(gb, (const char*)Bs + chunk * 1024);
    }
    __syncthreads();

    short8 af[4], bfr[4];
#pragma unroll
    for (int mi = 0; mi < 4; ++mi)
      af[mi] = *(const short8*)(As + (wm + mi * 16 + lane15) * BK + quad * 8);
#pragma unroll
    for (int ni = 0; ni < 4; ++ni)
      bfr[ni] = *(const short8*)(Bs + (wn + ni * 16 + lane15) * BK + quad * 8);
#pragma unroll
    for (int mi = 0; mi < 4; ++mi)
#pragma unroll
      for (int ni = 0; ni < 4; ++ni)
        acc[mi][ni] = __builtin_amdgcn_mfma_f32_16x16x32_bf16(
            af[mi], bfr[ni], acc[mi][ni], 0, 0, 0);
    __syncthreads();
  }

#pragma unroll
  for (int mi = 0; mi < 4; ++mi) {
    const long rbase = row0 + wm + mi * 16 + quad * 4;
#pragma unroll
    for (int ni = 0; ni < 4; ++ni) {
      const int c = col0 + wn + ni * 16 + lane15;
#pragma unroll
      for (int r = 0; r < 4; ++r)
        C[(rbase + r) * Ndim + c] = acc[mi][ni][r];
    }
  }
}

// ------------------------------- launch -------------------------------------
extern "C" void kernel_launch(void* const* d_in, const int* in_sizes, int n_in,
                              void* d_out, int out_size, void* d_ws, size_t ws_size,
                              hipStream_t stream) {
  const float* x   = (const float*)d_in[0];
  const float* Wp  = (const float*)d_in[1];
  const float* Wc  = (const float*)d_in[2];
  const float* phi = (const float*)d_in[3];
  float* out = (float*)d_out;

  // ws: Qbf @0 (67108864 B), Wpbf @67108864 (2 MB), Wcbf @69206016 (2 MB)
  char* ws = (char*)d_ws;
  unsigned short* Qbf  = (unsigned short*)(ws);
  unsigned short* Wpbf = (unsigned short*)(ws + (size_t)67108864);
  unsigned short* Wcbf = (unsigned short*)(ws + (size_t)69206016);

  cast_w<<<2048, 256, 0, stream>>>(Wp, Wc, Wpbf, Wcbf);
  gemm1_fused<<<2048, 256, 0, stream>>>(x, Wpbf, phi, Qbf);
  gemm2_bt<<<2048, 256, 0, stream>>>(Qbf, Wcbf, out);

  (void)in_sizes; (void)n_in; (void)out_size; (void)ws_size;
}

// Round 3
// 390.029 us; speedup vs baseline: 1.1185x; 1.1185x over previous
//
#include <hip/hip_runtime.h>
#include <cstdint>
#include <cstddef>

// ---------------------------------------------------------------------------
// out = cos(x @ Wp^T + phi) @ Wc^T
//   x: [32768,1024] fp32, Wp/Wc: [1024,1024] fp32, phi flat [1024] fp32.
// R3: revert R2's cast-fusion (it doubled A-side HBM traffic). Single merged
// cast dispatch; GEMM grid swizzled so the 8 n-blocks sharing an m-block's A
// rows map to the SAME XCD (blockIdx % 8 invariant) -> A L2-resident once.
// GEMM core: m97 structure, 128x128 tile, BK=32, 16x16x32 bf16 MFMA.
// ---------------------------------------------------------------------------

typedef __attribute__((ext_vector_type(8))) short short8;
typedef __attribute__((ext_vector_type(4))) float f32x4;

__device__ __forceinline__ unsigned short f2bf(float f) {
  unsigned u = __float_as_uint(f);
  u += 0x7FFFu + ((u >> 16) & 1u);   // RNE
  return (unsigned short)(u >> 16);
}

__device__ __forceinline__ void async_load16(const void* g, const void* l) {
  __builtin_amdgcn_global_load_lds(
      (const __attribute__((address_space(1))) void*)g,
      (__attribute__((address_space(3))) void*)l,
      16, 0, 0);
}

// ------------------- x + Wp + Wc fp32 -> bf16, ONE dispatch -----------------
__global__ __launch_bounds__(256) void cast_all(
    const float* __restrict__ x, const float* __restrict__ Wp,
    const float* __restrict__ Wc, unsigned short* __restrict__ xb,
    unsigned short* __restrict__ wpb, unsigned short* __restrict__ wcb) {
  long i = ((long)blockIdx.x * 256 + threadIdx.x) * 4;  // < 35651584
  const float* s;
  unsigned short* d;
  long j;
  if (i < 33554432)      { s = x;  d = xb;  j = i; }
  else if (i < 34603008) { s = Wp; d = wpb; j = i - 33554432; }
  else                   { s = Wc; d = wcb; j = i - 34603008; }
  const float4 v = *(const float4*)(s + j);
  ushort4 o;
  o.x = f2bf(v.x); o.y = f2bf(v.y); o.z = f2bf(v.z); o.w = f2bf(v.w);
  *(ushort4*)(d + j) = o;
}

constexpr int TM = 128, TN = 128, BK = 32;
constexpr int Kdim = 1024, Ndim = 1024;

// C[m,n] = sum_k A[m,k]*B[n,k]  (B row-major [N,K]).
// EPI==1: store bf16 cos(acc + phi[n]); EPI==0: store fp32 acc.
template <int EPI>
__global__ __launch_bounds__(256, 2) void gemm_bt(
    const unsigned short* __restrict__ A,   // [M,1024] bf16
    const unsigned short* __restrict__ B,   // [1024,1024] bf16
    const float* __restrict__ phi,
    void* __restrict__ Cout) {
  __shared__ unsigned short As[TM * BK];    // 8 KB
  __shared__ unsigned short Bs[TN * BK];    // 8 KB

  const int tid  = threadIdx.x;
  const int lane = tid & 63;
  const int wv   = tid >> 6;
  // XCD-swizzle: all 8 n-siblings of an m-block keep blockIdx % 8 == m_blk % 8
  // (256 | 8*k), so they land on the same XCD and share its L2 copy of A.
  const int m_blk = blockIdx.x & 255;
  const int n_blk = blockIdx.x >> 8;
  const long row0 = (long)m_blk * TM;
  const int  col0 = n_blk * TN;

  // staging: chunk = 16 rows (1024 B); lane covers row = chunk*16 + lane/4,
  // byte col (lane&3)*16.  LDS dest = wave-uniform base + lane*16 (HW rule).
  const int s_row  = lane >> 2;
  const int s_colb = (lane & 3) * 16;

  const int lane15 = lane & 15;
  const int quad   = lane >> 4;
  const int wm = (wv >> 1) * 64;
  const int wn = (wv & 1) * 64;

  f32x4 acc[4][4];
#pragma unroll
  for (int mi = 0; mi < 4; ++mi)
#pragma unroll
    for (int ni = 0; ni < 4; ++ni) {
      f32x4 z = {0.f, 0.f, 0.f, 0.f};
      acc[mi][ni] = z;
    }

  for (int k0 = 0; k0 < Kdim; k0 += BK) {
#pragma unroll
    for (int j = 0; j < 2; ++j) {
      const int chunk = wv * 2 + j;              // 0..7
      const int row = chunk * 16 + s_row;        // 0..127
      const char* ga = (const char*)(A + (row0 + row) * Kdim + k0) + s_colb;
      async_load16(ga, (const char*)As + chunk * 1024);
      const char* gb = (const char*)(B + (long)(col0 + row) * Kdim + k0) + s_colb;
      async_load16(gb, (const char*)Bs + chunk * 1024);
    }
    __syncthreads();

    short8 af[4], bfr[4];
#pragma unroll
    for (int mi = 0; mi < 4; ++mi)
      af[mi] = *(const short8*)(As + (wm + mi * 16 + lane15) * BK + quad * 8);
#pragma unroll
    for (int ni = 0; ni < 4; ++ni)
      bfr[ni] = *(const short8*)(Bs + (wn + ni * 16 + lane15) * BK + quad * 8);
#pragma unroll
    for (int mi = 0; mi < 4; ++mi)
#pragma unroll
      for (int ni = 0; ni < 4; ++ni)
        acc[mi][ni] = __builtin_amdgcn_mfma_f32_16x16x32_bf16(
            af[mi], bfr[ni], acc[mi][ni], 0, 0, 0);
    __syncthreads();
  }

  // C/D layout (m89-verified): col = lane&15, row = quad*4 + reg.
  if (EPI == 1) {
    unsigned short* Q = (unsigned short*)Cout;
    float ph[4];
#pragma unroll
    for (int ni = 0; ni < 4; ++ni)
      ph[ni] = phi[col0 + wn + ni * 16 + lane15];
#pragma unroll
    for (int mi = 0; mi < 4; ++mi) {
      const long rbase = row0 + wm + mi * 16 + quad * 4;
#pragma unroll
      for (int ni = 0; ni < 4; ++ni) {
        const int c = col0 + wn + ni * 16 + lane15;
#pragma unroll
        for (int r = 0; r < 4; ++r) {
          float v = __cosf(acc[mi][ni][r] + ph[ni]);
          Q[(rbase + r) * Ndim + c] = f2bf(v);
        }
      }
    }
  } else {
    float* C = (float*)Cout;
#pragma unroll
    for (int mi = 0; mi < 4; ++mi) {
      const long rbase = row0 + wm + mi * 16 + quad * 4;
#pragma unroll
      for (int ni = 0; ni < 4; ++ni) {
        const int c = col0 + wn + ni * 16 + lane15;
#pragma unroll
        for (int r = 0; r < 4; ++r)
          C[(rbase + r) * Ndim + c] = acc[mi][ni][r];
      }
    }
  }
}

// ------------------------------- launch -------------------------------------
extern "C" void kernel_launch(void* const* d_in, const int* in_sizes, int n_in,
                              void* d_out, int out_size, void* d_ws, size_t ws_size,
                              hipStream_t stream) {
  const float* x   = (const float*)d_in[0];
  const float* Wp  = (const float*)d_in[1];
  const float* Wc  = (const float*)d_in[2];
  const float* phi = (const float*)d_in[3];
  float* out = (float*)d_out;

  // ws: Abf @0 (64 MB), Qbf @64 MB (64 MB), Wpbf @128 MB (2 MB), Wcbf (2 MB)
  char* ws = (char*)d_ws;
  unsigned short* Abf  = (unsigned short*)(ws);
  unsigned short* Qbf  = (unsigned short*)(ws + (size_t)67108864);
  unsigned short* Wpbf = (unsigned short*)(ws + (size_t)134217728);
  unsigned short* Wcbf = (unsigned short*)(ws + (size_t)136314880);

  cast_all<<<34816, 256, 0, stream>>>(x, Wp, Wc, Abf, Wpbf, Wcbf);
  gemm_bt<1><<<2048, 256, 0, stream>>>(Abf, Wpbf, phi, (void*)Qbf);
  gemm_bt<0><<<2048, 256, 0, stream>>>(Qbf, Wcbf, nullptr, (void*)out);

  (void)in_sizes; (void)n_in; (void)out_size; (void)ws_size;
}